// Round 1
// baseline (72.221 us; speedup 1.0000x reference)
//
#include <hip/hip_runtime.h>
#include <math.h>

// Problem constants (from reference):
//   T = 131072 frames, N = 522 landmarks, 3 coords, f32 in / f32 out
//   out = (T, 39):
//     [0:5)   flex per finger
//     [5]     thumb angle
//     [6:10)  zeros
//     [10:16) palm center (x,y,z,x,y,z)
//     [16:22) palm normal (x,y,z,x,y,z)
//     [22:25) dc   (center[t]-center[t-1], 0 at t=0)
//     [25:28) d2c  (c[t]-2c[t-1]+c[t-2], 0 at t<2)
//     [28:34) zeros
//     [34]    gaze  = |pose0 - pose7|
//     [35]    aperture = |max(mouth)-min(mouth)| (per-coord extent, then L2)
//     [36]    0.5
//     [37:39) zeros

constexpr int T_FRAMES = 131072;
constexpr int ROWF = 522 * 3;   // 1566 floats = 6264 bytes per frame (8B aligned)
constexpr float EPS = 1e-8f;

struct F3 { float x, y, z; };

__device__ __forceinline__ F3 ld3(const float* __restrict__ p) {
    F3 r; r.x = p[0]; r.y = p[1]; r.z = p[2]; return r;
}
__device__ __forceinline__ F3 sub3(F3 a, F3 b) { return {a.x-b.x, a.y-b.y, a.z-b.z}; }
__device__ __forceinline__ float dot3(F3 a, F3 b) { return a.x*b.x + a.y*b.y + a.z*b.z; }
__device__ __forceinline__ F3 cross3(F3 a, F3 b) {
    return {a.y*b.z - a.z*b.y, a.z*b.x - a.x*b.z, a.x*b.y - a.y*b.x};
}
__device__ __forceinline__ float vangle(F3 a, F3 b) {
    float na = sqrtf(dot3(a, a));
    float nb = sqrtf(dot3(b, b));
    float c = dot3(a, b) / (na * nb + EPS);
    c = fminf(1.0f, fmaxf(-1.0f, c));
    return acosf(c);
}

// mean of hand points {0,1,5,9,13,17} of a row
__device__ __forceinline__ F3 palm_center(const float* __restrict__ row) {
    F3 s = ld3(row + 0 * 3);
    F3 p;
    p = ld3(row + 1 * 3);  s.x += p.x; s.y += p.y; s.z += p.z;
    p = ld3(row + 5 * 3);  s.x += p.x; s.y += p.y; s.z += p.z;
    p = ld3(row + 9 * 3);  s.x += p.x; s.y += p.y; s.z += p.z;
    p = ld3(row + 13 * 3); s.x += p.x; s.y += p.y; s.z += p.z;
    p = ld3(row + 17 * 3); s.x += p.x; s.y += p.y; s.z += p.z;
    const float inv6 = 1.0f / 6.0f;
    return {s.x * inv6, s.y * inv6, s.z * inv6};
}

__global__ __launch_bounds__(256) void feat_kernel(
        const float* __restrict__ lm, float* __restrict__ out) {
    const int t = blockIdx.x * blockDim.x + threadIdx.x;
    if (t >= T_FRAMES) return;
    const float* __restrict__ row = lm + (long long)t * ROWF;

    // ---- load hand points 0..20 (63 contiguous floats) via float2 ----
    float hf[63];
    const float2* __restrict__ r2 = (const float2*)row;  // rows are 8B aligned
    #pragma unroll
    for (int i = 0; i < 31; ++i) {
        float2 v = r2[i];
        hf[2 * i] = v.x; hf[2 * i + 1] = v.y;
    }
    hf[62] = row[62];

    #define H(i) (F3{hf[(i) * 3], hf[(i) * 3 + 1], hf[(i) * 3 + 2]})

    float feat[39];

    // ---- finger flex ----
    {
        const int F0[5] = {1, 5, 9, 13, 17};
        #pragma unroll
        for (int f = 0; f < 5; ++f) {
            const int a = F0[f];
            F3 p0 = H(a), p1 = H(a + 1), p2 = H(a + 2), p3 = H(a + 3);
            F3 v1 = sub3(p1, p0), v2 = sub3(p2, p1), v3 = sub3(p3, p2);
            feat[f] = vangle(v1, v2) + vangle(v2, v3);
        }
    }
    // thumb
    feat[5] = vangle(sub3(H(4), H(2)), sub3(H(5), H(1)));
    feat[6] = 0.f; feat[7] = 0.f; feat[8] = 0.f; feat[9] = 0.f;

    // ---- palm center ----
    F3 c;
    {
        F3 s = H(0);
        F3 p;
        p = H(1);  s.x += p.x; s.y += p.y; s.z += p.z;
        p = H(5);  s.x += p.x; s.y += p.y; s.z += p.z;
        p = H(9);  s.x += p.x; s.y += p.y; s.z += p.z;
        p = H(13); s.x += p.x; s.y += p.y; s.z += p.z;
        p = H(17); s.x += p.x; s.y += p.y; s.z += p.z;
        const float inv6 = 1.0f / 6.0f;
        c = {s.x * inv6, s.y * inv6, s.z * inv6};
    }
    feat[10] = c.x; feat[11] = c.y; feat[12] = c.z;
    feat[13] = c.x; feat[14] = c.y; feat[15] = c.z;

    // ---- orientation ----
    {
        F3 n = cross3(sub3(H(1), H(0)), sub3(H(5), H(0)));
        float nn = sqrtf(dot3(n, n)) + EPS;
        float inv = 1.0f / nn;
        feat[16] = n.x * inv; feat[17] = n.y * inv; feat[18] = n.z * inv;
        feat[19] = feat[16]; feat[20] = feat[17]; feat[21] = feat[18];
    }

    // ---- motion (recompute neighbor centers; rows are L1-hot from
    //      neighboring threads in this block) ----
    {
        F3 dc = {0.f, 0.f, 0.f}, d2c = {0.f, 0.f, 0.f};
        if (t >= 1) {
            F3 cm1 = palm_center(row - ROWF);
            dc = sub3(c, cm1);
            if (t >= 2) {
                F3 cm2 = palm_center(row - 2 * ROWF);
                d2c = {c.x - 2.f * cm1.x + cm2.x,
                       c.y - 2.f * cm1.y + cm2.y,
                       c.z - 2.f * cm1.z + cm2.z};
            }
        }
        feat[22] = dc.x;  feat[23] = dc.y;  feat[24] = dc.z;
        feat[25] = d2c.x; feat[26] = d2c.y; feat[27] = d2c.z;
        feat[28] = 0.f; feat[29] = 0.f; feat[30] = 0.f;
        feat[31] = 0.f; feat[32] = 0.f; feat[33] = 0.f;
    }

    // ---- gaze: pose[0]=landmark 489, pose[7]=landmark 496 ----
    {
        F3 a = ld3(row + 489 * 3);
        F3 b = ld3(row + 496 * 3);
        F3 g = sub3(a, b);
        feat[34] = sqrtf(dot3(g, g));
    }

    // ---- mouth aperture: landmarks 21 + MOUTH[i] ----
    {
        const int ML[20] = {82, 206, 61, 60, 58, 21, 288, 290, 291, 430,
                            312, 396, 342, 426, 335, 38, 105, 202, 112, 167};
        F3 p = ld3(row + ML[0] * 3);
        F3 mn = p, mx = p;
        #pragma unroll
        for (int i = 1; i < 20; ++i) {
            F3 q = ld3(row + ML[i] * 3);
            mn.x = fminf(mn.x, q.x); mn.y = fminf(mn.y, q.y); mn.z = fminf(mn.z, q.z);
            mx.x = fmaxf(mx.x, q.x); mx.y = fmaxf(mx.y, q.y); mx.z = fmaxf(mx.z, q.z);
        }
        F3 ap = sub3(mx, mn);
        feat[35] = sqrtf(dot3(ap, ap));
    }

    feat[36] = 0.5f; feat[37] = 0.f; feat[38] = 0.f;

    // ---- store 39 contiguous floats ----
    float* __restrict__ o = out + (long long)t * 39;
    #pragma unroll
    for (int i = 0; i < 39; ++i) o[i] = feat[i];

    #undef H
}

extern "C" void kernel_launch(void* const* d_in, const int* in_sizes, int n_in,
                              void* d_out, int out_size, void* d_ws, size_t ws_size,
                              hipStream_t stream) {
    const float* lm = (const float*)d_in[0];
    float* out = (float*)d_out;
    const int block = 256;
    const int grid = (T_FRAMES + block - 1) / block;
    feat_kernel<<<grid, block, 0, stream>>>(lm, out);
}

// Round 2
// 65.333 us; speedup vs baseline: 1.1054x; 1.1054x over previous
//
#include <hip/hip_runtime.h>
#include <math.h>

// out = (T, 39) f32; in = (T, 522, 3) f32.
// Layout per frame row (1566 floats = 6264 B, 8-B aligned):
//   hand = landmarks [0,21), face = [21,489), pose = [489,522)

constexpr int T_FRAMES = 131072;
constexpr int ROWF = 522 * 3;   // floats per frame
constexpr float EPS = 1e-8f;

struct F3 { float x, y, z; };

__device__ __forceinline__ F3 sub3(F3 a, F3 b) { return {a.x-b.x, a.y-b.y, a.z-b.z}; }
__device__ __forceinline__ float dot3(F3 a, F3 b) { return a.x*b.x + a.y*b.y + a.z*b.z; }
__device__ __forceinline__ F3 cross3(F3 a, F3 b) {
    return {a.y*b.z - a.z*b.y, a.z*b.x - a.x*b.z, a.x*b.y - a.y*b.x};
}
__device__ __forceinline__ float vangle(F3 a, F3 b) {
    float na = sqrtf(dot3(a, a));
    float nb = sqrtf(dot3(b, b));
    float c = dot3(a, b) / (na * nb + EPS);
    c = fminf(1.0f, fmaxf(-1.0f, c));
    return acosf(c);
}

// Load landmark i (i compile-time const after unroll) from an 8-B-aligned row
// using 2 loads instead of 3: byte offset 12*i; even i -> float2+float,
// odd i -> float+float2 (addr 12i+4 is 8-B aligned).
__device__ __forceinline__ F3 ldpt(const float* __restrict__ row, int i) {
    const float* p = row + i * 3;
    F3 r;
    if ((i & 1) == 0) {
        float2 v = *(const float2*)p;
        r.x = v.x; r.y = v.y; r.z = p[2];
    } else {
        float2 v = *(const float2*)(p + 1);
        r.x = p[0]; r.y = v.x; r.z = v.y;
    }
    return r;
}

// palm center = mean of hand points {0,1,5,9,13,17} from a global row
__device__ __forceinline__ F3 palm_center_g(const float* __restrict__ row) {
    F3 s = ldpt(row, 0);
    F3 p;
    p = ldpt(row, 1);  s.x += p.x; s.y += p.y; s.z += p.z;
    p = ldpt(row, 5);  s.x += p.x; s.y += p.y; s.z += p.z;
    p = ldpt(row, 9);  s.x += p.x; s.y += p.y; s.z += p.z;
    p = ldpt(row, 13); s.x += p.x; s.y += p.y; s.z += p.z;
    p = ldpt(row, 17); s.x += p.x; s.y += p.y; s.z += p.z;
    const float inv6 = 1.0f / 6.0f;
    return {s.x * inv6, s.y * inv6, s.z * inv6};
}

__global__ __launch_bounds__(256) void feat_kernel(
        const float* __restrict__ lm, float* __restrict__ out) {
    const int t = blockIdx.x * 256 + threadIdx.x;   // grid covers T exactly
    const float* __restrict__ row = lm + (long long)t * ROWF;

    // ---- hand points 0..20: 63 contiguous floats via 31 x float2 + 1 ----
    float hf[63];
    const float2* __restrict__ r2 = (const float2*)row;  // rows 8-B aligned
    #pragma unroll
    for (int i = 0; i < 31; ++i) {
        float2 v = r2[i];
        hf[2 * i] = v.x; hf[2 * i + 1] = v.y;
    }
    hf[62] = row[62];

    #define H(i) (F3{hf[(i) * 3], hf[(i) * 3 + 1], hf[(i) * 3 + 2]})

    float feat[39];

    // ---- finger flex + thumb ----
    {
        const int F0[5] = {1, 5, 9, 13, 17};
        #pragma unroll
        for (int f = 0; f < 5; ++f) {
            const int a = F0[f];
            F3 p0 = H(a), p1 = H(a + 1), p2 = H(a + 2), p3 = H(a + 3);
            F3 v1 = sub3(p1, p0), v2 = sub3(p2, p1), v3 = sub3(p3, p2);
            feat[f] = vangle(v1, v2) + vangle(v2, v3);
        }
    }
    feat[5] = vangle(sub3(H(4), H(2)), sub3(H(5), H(1)));
    feat[6] = 0.f; feat[7] = 0.f; feat[8] = 0.f; feat[9] = 0.f;

    // ---- palm center (this frame) ----
    F3 c;
    {
        F3 s = H(0);
        F3 p;
        p = H(1);  s.x += p.x; s.y += p.y; s.z += p.z;
        p = H(5);  s.x += p.x; s.y += p.y; s.z += p.z;
        p = H(9);  s.x += p.x; s.y += p.y; s.z += p.z;
        p = H(13); s.x += p.x; s.y += p.y; s.z += p.z;
        p = H(17); s.x += p.x; s.y += p.y; s.z += p.z;
        const float inv6 = 1.0f / 6.0f;
        c = {s.x * inv6, s.y * inv6, s.z * inv6};
    }
    feat[10] = c.x; feat[11] = c.y; feat[12] = c.z;
    feat[13] = c.x; feat[14] = c.y; feat[15] = c.z;

    // ---- orientation ----
    {
        F3 n = cross3(sub3(H(1), H(0)), sub3(H(5), H(0)));
        float inv = 1.0f / (sqrtf(dot3(n, n)) + EPS);
        feat[16] = n.x * inv; feat[17] = n.y * inv; feat[18] = n.z * inv;
        feat[19] = feat[16]; feat[20] = feat[17]; feat[21] = feat[18];
    }

    // ---- motion: neighbor centers via intra-wave shuffle (no LDS/barrier);
    //      lanes 0,1 recompute from global (2/64 lanes) ----
    {
        float c1x = __shfl_up(c.x, 1), c1y = __shfl_up(c.y, 1), c1z = __shfl_up(c.z, 1);
        float c2x = __shfl_up(c.x, 2), c2y = __shfl_up(c.y, 2), c2z = __shfl_up(c.z, 2);
        F3 cm1 = {c1x, c1y, c1z};
        F3 cm2 = {c2x, c2y, c2z};
        const int lane = threadIdx.x & 63;
        if (lane < 2) {
            if (t >= 1) cm1 = palm_center_g(row - ROWF);
            if (t >= 2) cm2 = palm_center_g(row - 2 * ROWF);
        }
        F3 dc = {0.f, 0.f, 0.f}, d2c = {0.f, 0.f, 0.f};
        if (t >= 1) {
            dc = sub3(c, cm1);
            if (t >= 2) {
                d2c = {c.x - 2.f * cm1.x + cm2.x,
                       c.y - 2.f * cm1.y + cm2.y,
                       c.z - 2.f * cm1.z + cm2.z};
            }
        }
        feat[22] = dc.x;  feat[23] = dc.y;  feat[24] = dc.z;
        feat[25] = d2c.x; feat[26] = d2c.y; feat[27] = d2c.z;
        feat[28] = 0.f; feat[29] = 0.f; feat[30] = 0.f;
        feat[31] = 0.f; feat[32] = 0.f; feat[33] = 0.f;
    }

    // ---- gaze: pose[0]=lm 489, pose[7]=lm 496 ----
    {
        F3 a = ldpt(row, 489);
        F3 b = ldpt(row, 496);
        F3 g = sub3(a, b);
        feat[34] = sqrtf(dot3(g, g));
    }

    // ---- mouth aperture: absolute landmark indices (21 + MOUTH[i]) ----
    {
        const int ML[20] = {82, 206, 61, 60, 58, 21, 288, 290, 291, 430,
                            312, 396, 342, 426, 335, 38, 105, 202, 112, 167};
        F3 p = ldpt(row, ML[0]);
        F3 mn = p, mx = p;
        #pragma unroll
        for (int i = 1; i < 20; ++i) {
            F3 q = ldpt(row, ML[i]);
            mn.x = fminf(mn.x, q.x); mn.y = fminf(mn.y, q.y); mn.z = fminf(mn.z, q.z);
            mx.x = fmaxf(mx.x, q.x); mx.y = fmaxf(mx.y, q.y); mx.z = fmaxf(mx.z, q.z);
        }
        F3 ap = sub3(mx, mn);
        feat[35] = sqrtf(dot3(ap, ap));
    }

    feat[36] = 0.5f; feat[37] = 0.f; feat[38] = 0.f;

    float* __restrict__ o = out + (long long)t * 39;
    #pragma unroll
    for (int i = 0; i < 39; ++i) o[i] = feat[i];

    #undef H
}

extern "C" void kernel_launch(void* const* d_in, const int* in_sizes, int n_in,
                              void* d_out, int out_size, void* d_ws, size_t ws_size,
                              hipStream_t stream) {
    const float* lm = (const float*)d_in[0];
    float* out = (float*)d_out;
    feat_kernel<<<T_FRAMES / 256, 256, 0, stream>>>(lm, out);
}